// Round 3
// baseline (90.726 us; speedup 1.0000x reference)
//
#include <hip/hip_runtime.h>

// IGD metric kernel for MI355X (gfx950) — R18: occupancy experiment (3 -> 4 waves/SIMD).
// d2(i,j) = pfsq[i] + xsq[j] + dot(e4m3(-2*pf_i), e4m3(x_j)); norms in fp32 from the HW-DECODED
// fp8 bytes -> d2 = exact sq-distance of rounded points regardless of HW rounding mode.
// R17 post-mortem: barrier-free direct-L2 ring landed AT the plateau (87.3 vs 87.2) -> 14 null
// variants across two delivery structures. Delivery, barriers, and VALU count all exonerated.
// The only invariant left: occupancy = 3 waves/SIMD (768 blocks = 3/CU, ~150 VGPR). Issue math
// says pipes would be ~full at 3 waves IF waves never co-stalled; measured ~670cy/unit vs ~430
// modeled -> in-order MFMA-latency + vmcnt stalls that 3 waves can't cover = latency-bound.
// R18: pure TLP change. NSPLIT 12->16 (1024 blocks = 4 blocks/CU, uniform 32 units/split),
// __launch_bounds__(256,4) (VGPR<=128), prefetch ring depth 4->2 to fit the register budget
// (persistent ~90 + 32 transient acc ~= 122 < 128). Everything else byte-identical to R17.
// Harness poison fill of ws (~41.5 us @6.5TB/s) is a fixed floor inside the timed window.

typedef float f32x16 __attribute__((ext_vector_type(16)));
typedef float f32x2 __attribute__((ext_vector_type(2)));
typedef int i32x8 __attribute__((ext_vector_type(8)));
typedef unsigned long long u64;

#define DIM 64
#define NSPLIT 16
#define UNITB 2048            // bytes per 32-col unit: 4 qfrags x 64 lanes x 8 B
#define MTILE 256             // rows per block (4 waves x 64 rows)

union BFrag { u64 q[4]; i32x8 v; };

// ---------------- pack (HW fp8 converters) ----------------
// encode16: 16 fp32 (optionally pre-scaled) -> 2 u64 of e4m3 bytes + exact fp32 sum of squares
// of the DECODED values (consistency: d2 is then an exact distance between rounded points).
__device__ __forceinline__ void encode16(const float* f, u64 w[2], float& sumsq) {
    unsigned int w32[4];
#pragma unroll
    for (int k = 0; k < 4; ++k) {
        int lo = __builtin_amdgcn_cvt_pk_fp8_f32(f[4 * k],     f[4 * k + 1], 0,  false);
        w32[k] = __builtin_amdgcn_cvt_pk_fp8_f32(f[4 * k + 2], f[4 * k + 3], lo, true);
    }
#pragma unroll
    for (int k = 0; k < 4; ++k) {
        f32x2 d0 = __builtin_amdgcn_cvt_pk_f32_fp8(w32[k], false);
        f32x2 d1 = __builtin_amdgcn_cvt_pk_f32_fp8(w32[k], true);
        sumsq += d0.x * d0.x + d0.y * d0.y + d1.x * d1.x + d1.y * d1.y;
    }
    w[0] = (u64)w32[0] | ((u64)w32[1] << 32);
    w[1] = (u64)w32[2] | ((u64)w32[3] << 32);
}

// Bp layout (32x32x64 B-operand): lane L = h*32 + c31 holds col = u*32+c31, k = h*32 + 0..31:
//   Bp[u*2048 + q*512 + L*8 + b] = e4m3(x[col][h*32 + q*8 + b]).
// xsq[col] = exact fp32 sum of squares of decoded values.
// pf -> Ab row-major fp8(-2*pf) (A-operand = contiguous 32 B per lane); pfsq = 0.25*sum(dec^2).
__global__ void pack_kernel(const float* __restrict__ x, const float* __restrict__ pf,
                            unsigned char* __restrict__ Bp, unsigned char* __restrict__ Ab,
                            float* __restrict__ xsq, float* __restrict__ pfsq,
                            float* __restrict__ out, int N, int M) {
    int gid = blockIdx.x * blockDim.x + threadIdx.x;
    if (gid == 0) out[0] = 0.f;
    if (gid < N * 4) {
        int col = gid >> 2, t = gid & 3;
        const float* s = x + (size_t)col * DIM + t * 16;
        float4 v0 = *(const float4*)(s);
        float4 v1 = *(const float4*)(s + 4);
        float4 v2 = *(const float4*)(s + 8);
        float4 v3 = *(const float4*)(s + 12);
        float f[16] = {v0.x, v0.y, v0.z, v0.w, v1.x, v1.y, v1.z, v1.w,
                       v2.x, v2.y, v2.z, v2.w, v3.x, v3.y, v3.z, v3.w};
        float partial = 0.f;
        u64 w[2];
        encode16(f, w, partial);
        int u = col >> 5, c31 = col & 31;
        unsigned char* ub = Bp + (size_t)u * UNITB;
        int h = t >> 1;
#pragma unroll
        for (int ss = 0; ss < 2; ++ss) {
            int q = (t & 1) * 2 + ss;
            *(u64*)(ub + (size_t)q * 512 + (size_t)(h * 32 + c31) * 8) = w[ss];
        }
        partial += __shfl_xor(partial, 1);
        partial += __shfl_xor(partial, 2);
        if (t == 0) xsq[col] = partial;
    } else {
        int g = gid - N * 4;
        int row = g >> 2, q = g & 3;
        if (row >= M) return;
        const float* s = pf + (size_t)row * DIM + q * 16;
        float4 v0 = *(const float4*)(s);
        float4 v1 = *(const float4*)(s + 4);
        float4 v2 = *(const float4*)(s + 8);
        float4 v3 = *(const float4*)(s + 12);
        float f[16] = {v0.x, v0.y, v0.z, v0.w, v1.x, v1.y, v1.z, v1.w,
                       v2.x, v2.y, v2.z, v2.w, v3.x, v3.y, v3.z, v3.w};
#pragma unroll
        for (int j = 0; j < 16; ++j) f[j] *= -2.f;
        float partial = 0.f;
        u64 w[2];
        encode16(f, w, partial);
        *(u64*)(Ab + (size_t)row * DIM + q * 16)     = w[0];
        *(u64*)(Ab + (size_t)row * DIM + q * 16 + 8) = w[1];
        partial += __shfl_xor(partial, 1);
        partial += __shfl_xor(partial, 2);
        if (q == 0) pfsq[row] = partial * 0.25f;
    }
}

// ---------------- main: barrier-free, direct-L2 B stream, K=64 fp8 GEMM + row-min ----------
// No LDS, no __syncthreads. Each wave owns 64 rows and streams its split's B units from L2
// (Bp = 1 MB, resident in every XCD's 4 MB L2) through a depth-2 register prefetch ring.
// 4 blocks/CU (16 waves/CU, 4/SIMD) for latency hiding.
__global__ __launch_bounds__(256, 4)
void igd_main(const unsigned char* __restrict__ A, const unsigned char* __restrict__ Bp,
              const float* __restrict__ xsq, float* __restrict__ partial, int N) {
    const int tid = threadIdx.x;
    const int mTile  = blockIdx.x;
    const int nsplit = blockIdx.y;
    const int lane = tid & 63;
    const int wave = tid >> 6;
    const int half = lane >> 5;
    const int l31  = lane & 31;
    const int rowBase = mTile * MTILE + wave * 64;

    // ragged split over 32-col units (N=16384 -> uniform 32 units/split)
    const int utotal = N / 32;
    const int ubase  = utotal / NSPLIT;
    const int urem   = utotal % NSPLIT;
    const int ustart = nsplit * ubase + (nsplit < urem ? nsplit : urem);
    const int ucount = ubase + (nsplit < urem ? 1 : 0);

    // Persistent A operands: lane holds A[row = l31 + 32g][k = half*32 .. +31] (32 B contiguous)
    BFrag a[2];
#pragma unroll
    for (int g = 0; g < 2; ++g) {
        const unsigned char* ap = A + (size_t)(rowBase + 32 * g + l31) * DIM + half * 32;
#pragma unroll
        for (int qq = 0; qq < 4; ++qq)
            a[g].q[qq] = *(const u64*)(ap + qq * 8);
    }

    // per-lane global base pointers for the B stream and xsq
    const unsigned char* bG = Bp + (size_t)ustart * UNITB + lane * 8;
    const float* xG = xsq + ustart * 32 + l31;

    // direct global load of one 32x32x64 B fragment (4x global_load_dwordx2, coalesced 512B/quad)
#define LOADG(rr, u)                                                           \
    {                                                                          \
        const unsigned char* p = bG + (size_t)(u) * UNITB;                     \
        rr.q[0] = *(const u64*)(p);                                            \
        rr.q[1] = *(const u64*)(p + 512);                                      \
        rr.q[2] = *(const u64*)(p + 1024);                                     \
        rr.q[3] = *(const u64*)(p + 1536);                                     \
    }

    f32x16 zero, m0, m1;
#pragma unroll
    for (int r = 0; r < 16; ++r) { zero[r] = 0.f; m0[r] = 1e30f; m1[r] = 1e30f; }

    // Unity E8M0 scales (0x7F = 2^0): bit-identical to non-scaled fp8 accumulation.
#define MFMA2(accA, accB, bfrag)                                               \
    {                                                                          \
        accA = __builtin_amdgcn_mfma_scale_f32_32x32x64_f8f6f4(                \
            a[0].v, bfrag.v, zero, 0, 0, 0, 0x7F7F7F7F, 0, 0x7F7F7F7F);        \
        accB = __builtin_amdgcn_mfma_scale_f32_32x32x64_f8f6f4(                \
            a[1].v, bfrag.v, zero, 0, 0, 0, 0x7F7F7F7F, 0, 0x7F7F7F7F);        \
    }

#define MINS(accA, accB, xq0)                                                  \
    {                                                                          \
        _Pragma("unroll")                                                      \
        for (int r = 0; r < 16; ++r) {                                         \
            m0[r] = fminf(m0[r], accA[r] + (xq0));                             \
            m1[r] = fminf(m1[r], accB[r] + (xq0));                             \
        }                                                                      \
    }

    // depth-2 prefetch ring (~400cy/wave of cover vs ~200cy L2-hit latency; 4 waves/SIMD add
    // cross-wave cover). Static slot indices only (rule #20), via unrolled steps.
    BFrag b[2];
    float xq[2];
#pragma unroll
    for (int i = 0; i < 2; ++i) {      // prologue: units 0..1 (ucount = 32 at N=16384)
        LOADG(b[i], i);
        xq[i] = xG[(size_t)i * 32];
    }

    const int umain = ucount & ~1;
    for (int u = 0; u < umain; u += 2) {
#pragma unroll
        for (int s = 0; s < 2; ++s) {
            f32x16 acA, acB;
            MFMA2(acA, acB, b[s]);               // consumes b[s] at issue
            const float x0 = xq[s];
            // prefetch unit u+2+s into the slot just consumed. Last main iteration over-reads
            // up to 2 units past the split into adjacent ws regions (Ab/pfsq) — valid memory,
            // values never computed. Keeps the hot loop branchless.
            LOADG(b[s], u + 2 + s);
            xq[s] = xG[(size_t)(u + 2 + s) * 32];
            MINS(acA, acB, x0);                  // dependent VALU runs under the new loads
        }
    }
    // tail: remaining 0..1 unit already resident in slot 0
    if (umain < ucount) {
        f32x16 acA, acB;
        MFMA2(acA, acB, b[0]);
        MINS(acA, acB, xq[0]);
    }
#undef LOADG
#undef MFMA2
#undef MINS

    // cross-lane min over the 32 lanes sharing a row
#pragma unroll
    for (int mask = 1; mask <= 16; mask <<= 1) {
#pragma unroll
        for (int r = 0; r < 16; ++r) {
            m0[r] = fminf(m0[r], __shfl_xor(m0[r], mask));
            m1[r] = fminf(m1[r], __shfl_xor(m1[r], mask));
        }
    }
    if (l31 == 0) {
        // C/D layout (shape-determined, FMT-independent): row = (r&3)+8*(r>>2)+4*half
#pragma unroll
        for (int r = 0; r < 16; ++r) {
            int row0 = rowBase + (r & 3) + 8 * (r >> 2) + 4 * half;
            partial[(size_t)row0 * NSPLIT + nsplit] = m0[r];
            partial[(size_t)(row0 + 32) * NSPLIT + nsplit] = m1[r];
        }
    }
}

// ---------------- reduce: min over splits, add pfsq, sqrt, mean ----------------
__global__ void reduce_kernel(const float* __restrict__ partial, const float* __restrict__ pfsq,
                              float* __restrict__ out, int M, float invM) {
    int row = blockIdx.x * blockDim.x + threadIdx.x;
    float v = 0.f;
    if (row < M) {
        const float* p = partial + (size_t)row * NSPLIT;
        float mn = 3.4e38f;
#pragma unroll
        for (int s = 0; s < NSPLIT; ++s) mn = fminf(mn, p[s]);
        float d2 = mn + pfsq[row];
        v = sqrtf(fmaxf(d2, 0.f)) * invM;
    }
#pragma unroll
    for (int m = 1; m < 64; m <<= 1) v += __shfl_xor(v, m);
    __shared__ float wsum[4];
    int lane = threadIdx.x & 63, w = threadIdx.x >> 6;
    if (lane == 0) wsum[w] = v;
    __syncthreads();
    if (threadIdx.x == 0) atomicAdd(out, wsum[0] + wsum[1] + wsum[2] + wsum[3]);
}

extern "C" void kernel_launch(void* const* d_in, const int* in_sizes, int n_in,
                              void* d_out, int out_size, void* d_ws, size_t ws_size,
                              hipStream_t stream) {
    const float* x  = (const float*)d_in[0];   // [N, 64]
    const float* pf = (const float*)d_in[1];   // [M, 64]
    const int N = in_sizes[0] / DIM;
    const int M = in_sizes[1] / DIM;

    char* ws = (char*)d_ws;
    unsigned char* Bp = (unsigned char*)ws;                        // N*64 bytes (packed fp8)
    unsigned char* Ab = (unsigned char*)(ws + (size_t)N * DIM);    // M*64 bytes
    float* xsq  = (float*)(ws + (size_t)(N + M) * DIM);            // N floats
    float* pfsq = xsq + N;                                         // M floats
    float* part = pfsq + M;                                        // M*NSPLIT floats

    int packThreads = (N + M) * 4;
    pack_kernel<<<dim3((packThreads + 255) / 256), 256, 0, stream>>>(
        x, pf, Bp, Ab, xsq, pfsq, (float*)d_out, N, M);
    igd_main<<<dim3(M / MTILE, NSPLIT), 256, 0, stream>>>(Ab, Bp, xsq, part, N);
    reduce_kernel<<<dim3((M + 255) / 256), 256, 0, stream>>>(part, pfsq, (float*)d_out, M, 1.f / (float)M);
}